// Round 5
// baseline (467.146 us; speedup 1.0000x reference)
//
#include <hip/hip_runtime.h>
#include <hip/hip_bf16.h>
#include <math.h>

#define N_TOK 4096
#define DIM   1024
#define NEXP  8
#define IDIM  2048
#define TWOI  4096
#define CAP   1280

#define W1_BLOCKS (64 * 16 * NEXP)   // 8192 transpose tiles for W1
#define W2_BLOCKS (16 * 32 * NEXP)   // 4096 transpose tiles for W2
#define ROUTER_BLOCKS (N_TOK / 4)    // 1024

// gemm1 grid: x=16 n-tiles (128 i-cols + 128 g-cols each), y=5 m-tiles (256 rows),
// z = 8 experts + trans planes. 512-thread blocks; trans planes do 2 tiles each.
#define G1X 16
#define G1Y 5
#define G1_TRANS_Z ((W2_BLOCKS / 2 + G1X * G1Y - 1) / (G1X * G1Y))  // 26

using short8  = __attribute__((ext_vector_type(8))) short;
using floatx4 = __attribute__((ext_vector_type(4))) float;

__device__ __forceinline__ unsigned short f2b(float f) {
  __hip_bfloat16 h = __float2bfloat16(f);
  return *reinterpret_cast<unsigned short*>(&h);
}

// async global->LDS, 16B per lane. LDS dst = wave-uniform base; HW adds lane*16.
__device__ __forceinline__ void async16(const unsigned short* g, unsigned short* l) {
  __builtin_amdgcn_global_load_lds(
      (const __attribute__((address_space(1))) unsigned int*)g,
      (__attribute__((address_space(3))) unsigned int*)l,
      16, 0, 0);
}

// raw workgroup barrier with compiler fences (no vmcnt drain, unlike __syncthreads)
__device__ __forceinline__ void block_barrier() {
  __builtin_amdgcn_sched_barrier(0);
  asm volatile("" ::: "memory");
  __builtin_amdgcn_s_barrier();
  asm volatile("" ::: "memory");
  __builtin_amdgcn_sched_barrier(0);
}

// ---------------- prologue: W1 transpose+convert AND router ----------------
__global__ __launch_bounds__(256) void prologue_kernel(const float* __restrict__ W1,
                                                       unsigned short* __restrict__ w1t,
                                                       const float* __restrict__ x,
                                                       const float* __restrict__ Wg,
                                                       unsigned short* __restrict__ xb,
                                                       int* __restrict__ top_i,
                                                       float* __restrict__ gates) {
  __shared__ __align__(16) float smem_f[NEXP * DIM];   // 32 KB, overlaid
  int bid = blockIdx.x;
  int tid = threadIdx.x;

  if (bid < W1_BLOCKS) {
    float (*tile)[65] = reinterpret_cast<float (*)[65]>(smem_f);
    int e = bid >> 10;
    int t = bid & 1023;
    const int R = DIM, C = TWOI;
    int r0 = (t & 15) * 64;
    int c0 = (t >> 4) * 64;
    const float* s = W1 + (size_t)e * R * C;
    unsigned short* d = w1t + (size_t)e * R * C;
    int tr = tid >> 4, tc = (tid & 15) * 4;
#pragma unroll
    for (int i = 0; i < 4; i++) {
      float4 v = *reinterpret_cast<const float4*>(&s[(size_t)(r0 + tr + i * 16) * C + c0 + tc]);
      tile[tr + i * 16][tc]     = v.x;
      tile[tr + i * 16][tc + 1] = v.y;
      tile[tr + i * 16][tc + 2] = v.z;
      tile[tr + i * 16][tc + 3] = v.w;
    }
    __syncthreads();
#pragma unroll
    for (int j = 0; j < 4; j++) {
      int c = (tid >> 4) + j * 16;
      int r4 = (tid & 15) * 4;
      ushort4 o;
      o.x = f2b(tile[r4][c]);
      o.y = f2b(tile[r4 + 1][c]);
      o.z = f2b(tile[r4 + 2][c]);
      o.w = f2b(tile[r4 + 3][c]);
      *reinterpret_cast<ushort4*>(&d[(size_t)(c0 + c) * R + r0 + r4]) = o;
    }
  } else {
    int rb = bid - W1_BLOCKS;
    float* wg = smem_f;
    for (int i = tid * 4; i < NEXP * DIM; i += 256 * 4) {
      *reinterpret_cast<float4*>(wg + i) = *reinterpret_cast<const float4*>(Wg + i);
    }
    __syncthreads();
    int wave = tid >> 6, lane = tid & 63;
    int t = rb * 4 + wave;
    const float* xr = x + (size_t)t * DIM;
    unsigned short* xbr = xb + (size_t)t * DIM;
    double acc[NEXP];
#pragma unroll
    for (int e = 0; e < NEXP; e++) acc[e] = 0.0;
    for (int i = lane; i < DIM; i += 64) {
      float xf = xr[i];
      xbr[i] = f2b(xf);
      double xv = (double)xf;
#pragma unroll
      for (int e = 0; e < NEXP; e++) acc[e] += xv * (double)wg[e * DIM + i];
    }
#pragma unroll
    for (int e = 0; e < NEXP; e++) {
#pragma unroll
      for (int m = 1; m < 64; m <<= 1) acc[e] += __shfl_xor(acc[e], m, 64);
    }
    if (lane == 0) {
      int i0 = 0; double v0 = acc[0];
      for (int e = 1; e < NEXP; e++) { if (acc[e] > v0) { v0 = acc[e]; i0 = e; } }
      int i1 = -1; double v1 = -1e300;
      for (int e = 0; e < NEXP; e++) { if (e != i0 && acc[e] > v1) { v1 = acc[e]; i1 = e; } }
      double e1 = exp(v1 - v0);
      float g0 = (float)(1.0 / (1.0 + e1));
      float g1 = (float)(e1 / (1.0 + e1));
      top_i[t * 2] = i0; top_i[t * 2 + 1] = i1;
      gates[t * 2] = g0; gates[t * 2 + 1] = g1;
    }
  }
}

// ---------------- capacity scan (deterministic, token-major slot order) ----------------
__global__ __launch_bounds__(1024) void scan_kernel(const int* __restrict__ top_i,
                                                    const float* __restrict__ gates,
                                                    int* __restrict__ rowtok,
                                                    int* __restrict__ rowslot,
                                                    float* __restrict__ rowgate,
                                                    float* __restrict__ tokgate,
                                                    int* __restrict__ cnt) {
  __shared__ int hist[NEXP][1024];
  int t = threadIdx.x;
  int s0 = t * 8;
  int eloc[8];
  int c[NEXP];
#pragma unroll
  for (int e = 0; e < NEXP; e++) c[e] = 0;
#pragma unroll
  for (int j = 0; j < 8; j++) { int e = top_i[s0 + j]; eloc[j] = e; c[e]++; }
#pragma unroll
  for (int e = 0; e < NEXP; e++) hist[e][t] = c[e];
  __syncthreads();
  for (int step = 1; step < 1024; step <<= 1) {
    int tmp[NEXP];
#pragma unroll
    for (int e = 0; e < NEXP; e++) tmp[e] = (t >= step) ? hist[e][t - step] : 0;
    __syncthreads();
#pragma unroll
    for (int e = 0; e < NEXP; e++) hist[e][t] += tmp[e];
    __syncthreads();
  }
  int base[NEXP];
#pragma unroll
  for (int e = 0; e < NEXP; e++) base[e] = hist[e][t] - c[e];
  if (t < NEXP) {
    int tot = hist[t][1023];
    cnt[t] = tot < CAP ? tot : CAP;
  }
#pragma unroll
  for (int j = 0; j < 8; j++) {
    int s = s0 + j;
    int e = eloc[j];
    int pos = base[e]++;
    bool keep = pos < CAP;
    tokgate[s] = keep ? gates[s] : 0.0f;   // 0 marks a dropped slot (real gates are > 0)
    if (keep) {
      rowtok[e * CAP + pos]  = s >> 1;
      rowslot[e * CAP + pos] = s & 1;
      rowgate[e * CAP + pos] = gates[s];
    }
  }
}

// ---------------- GEMM1 + GLU, 8-phase schedule (z<8)  |  W2 transpose (z>=8) ----------------
// 256x(128i+128g) block tile, 8 waves, K-tile=32, 4 LDS buffers (128 KB), per-phase
// {ds_read ; stage-issue ; barrier ; setprio ; 16 MFMA ; setprio ; barrier}, counted vmcnt.
__global__ __launch_bounds__(512, 1) void gemm1_kernel(const unsigned short* __restrict__ xb,
                                                       const unsigned short* __restrict__ w1t,
                                                       const int* __restrict__ rowtok,
                                                       const int* __restrict__ cnt,
                                                       unsigned short* __restrict__ H,
                                                       const float* __restrict__ W2,
                                                       unsigned short* __restrict__ w2t) {
  __shared__ __align__(16) unsigned char smem[131072];  // 4 bufs x 32 KB | trans overlay 33 KB
  int tid = threadIdx.x;
  int z = blockIdx.z;

  if (z >= NEXP) {
    // ---- W2 transpose plane: 2 tiles per 512-thread block ----
    int slot = (z - NEXP) * (G1X * G1Y) + blockIdx.y * G1X + blockIdx.x;
    int half = tid >> 8, t2 = tid & 255;
    int id = slot * 2 + half;
    bool valid = (id < W2_BLOCKS);
    float* tile = (float*)smem + half * (64 * 65);   // [64][65] per half
    int tr = t2 >> 4, tc = (t2 & 15) * 4;
    const float* s = nullptr;
    unsigned short* d = nullptr;
    int r0 = 0, c0 = 0;
    if (valid) {
      int e = id >> 9;
      int t = id & 511;
      r0 = (t & 31) * 64;
      c0 = (t >> 5) * 64;
      s = W2 + (size_t)e * IDIM * DIM;
      d = w2t + (size_t)e * IDIM * DIM;
#pragma unroll
      for (int i = 0; i < 4; i++) {
        float4 v = *reinterpret_cast<const float4*>(&s[(size_t)(r0 + tr + i * 16) * DIM + c0 + tc]);
        tile[(tr + i * 16) * 65 + tc]     = v.x;
        tile[(tr + i * 16) * 65 + tc + 1] = v.y;
        tile[(tr + i * 16) * 65 + tc + 2] = v.z;
        tile[(tr + i * 16) * 65 + tc + 3] = v.w;
      }
    }
    __syncthreads();   // uniform: every thread reaches this regardless of valid
    if (valid) {
#pragma unroll
      for (int j = 0; j < 4; j++) {
        int c = (t2 >> 4) + j * 16;
        int r4 = (t2 & 15) * 4;
        ushort4 o;
        o.x = f2b(tile[r4 * 65 + c]);
        o.y = f2b(tile[(r4 + 1) * 65 + c]);
        o.z = f2b(tile[(r4 + 2) * 65 + c]);
        o.w = f2b(tile[(r4 + 3) * 65 + c]);
        *reinterpret_cast<ushort4*>(&d[(size_t)(c0 + c) * IDIM + r0 + r4]) = o;
      }
    }
    return;
  }

  // ---- gemm1 8-phase path ----
  int e  = z;
  int m0 = blockIdx.y * 256;
  int i0 = blockIdx.x * 128;
  int cnte = cnt[e];
  if (m0 >= cnte) return;   // uniform per block

  unsigned short* sm = (unsigned short*)smem;
  int lane = tid & 63, wave = tid >> 6;
  int lane16 = lane & 15, quad = lane >> 4;
  int wm = (wave & 1) * 128;     // wave row-half
  int wn = (wave >> 1) * 32;     // wave col-quarter (of 128)

  // per-thread staging sources (row = tid>>2, k-quad = (tid&3)*8 shorts)
  int rA = tid >> 2;             // 0..127
  int kq = (tid & 3) * 8;
  int tokA0 = (m0 + rA       < cnte) ? rowtok[e * CAP + m0 + rA      ] : 0;
  int tokA1 = (m0 + rA + 128 < cnte) ? rowtok[e * CAP + m0 + rA + 128] : 0;
  const unsigned short* w1e  = w1t + (size_t)e * TWOI * DIM;
  const unsigned short* gSA0 = xb + (size_t)tokA0 * DIM + kq;
  const unsigned short* gSA1 = xb + (size_t)tokA1 * DIM + kq;
  const unsigned short* gSBi = w1e + (size_t)(i0 + rA) * DIM + kq;
  const unsigned short* gSBg = w1e + (size_t)(i0 + rA + IDIM) * DIM + kq;

  // buffer b (32 KB = 16384 shorts): A [0,8192) shorts, Bi [8192,12288), Bg [12288,16384)
  auto stA = [&](int kt) {
    unsigned short* base = sm + (kt & 3) * 16384 + wave * 512;
    async16(gSA0 + kt * 32, base);            // rows 0..127
    async16(gSA1 + kt * 32, base + 4096);     // rows 128..255
  };
  auto stB = [&](int kt) {
    unsigned short* base = sm + (kt & 3) * 16384 + 8192 + wave * 512;
    async16(gSBi + kt * 32, base);            // Bi
    async16(gSBg + kt * 32, base + 4096);     // Bg
  };

  floatx4 acc_i[8][2], acc_g[8][2];
#pragma unroll
  for (int i = 0; i < 8; i++)
#pragma unroll
    for (int j = 0; j < 2; j++) {
      acc_i[i][j] = (floatx4){0.f, 0.f, 0.f, 0.f};
      acc_g[i][j] = (floatx4){0.f, 0.f, 0.f, 0.f};
    }

  // prologue: stage kt 0,1,2 (12 loads/thread in flight), ensure kt0 landed
  stA(0); stB(0); stA(1); stB(1); stA(2); stB(2);
  asm volatile("s_waitcnt vmcnt(8)" ::: "memory");
  block_barrier();

  const int NKT = DIM / 32;  // 32 K-tiles
  for (int kt = 0; kt < NKT; ++kt) {
    const unsigned short* Ab  = sm + (kt & 3) * 16384;
    const unsigned short* Bib = Ab + 8192;
    const unsigned short* Bgb = Ab + 12288;

    // ---- phase 0: rows wm..wm+63 ----
    short8 a[4], bi[2], bg[2];
#pragma unroll
    for (int i = 0; i < 4; i++)
      a[i] = *(const short8*)&Ab[(wm + i * 16 + lane16) * 32 + quad * 8];
#pragma unroll
    for (int j = 0; j < 2; j++) {
      bi[j] = *(const short8*)&Bib[(wn + j * 16 + lane16) * 32 + quad * 8];
      bg[j] = *(const short8*)&Bgb[(wn + j * 16 + lane16) * 32 + quad * 8];
    }
    if (kt + 3 < NKT) stA(kt + 3);
    block_barrier();
    __builtin_amdgcn_s_setprio(1);
#pragma unroll
    for (int j = 0; j < 2; j++)
#pragma unroll
      for (int i = 0; i < 4; i++) {
        acc_i[i][j] = __builtin_amdgcn_mfma_f32_16x16x32_bf16(a[i], bi[j], acc_i[i][j], 0, 0, 0);
        acc_g[i][j] = __builtin_amdgcn_mfma_f32_16x16x32_bf16(a[i], bg[j], acc_g[i][j], 0, 0, 0);
      }
    __builtin_amdgcn_s_setprio(0);
    block_barrier();

    // ---- phase 1: rows wm+64..wm+127 (reuse bi/bg) ----
#pragma unroll
    for (int i = 0; i < 4; i++)
      a[i] = *(const short8*)&Ab[(wm + 64 + i * 16 + lane16) * 32 + quad * 8];
    if (kt + 3 < NKT) stB(kt + 3);
    block_barrier();
    __builtin_amdgcn_s_setprio(1);
#pragma unroll
    for (int j = 0; j < 2; j++)
#pragma unroll
      for (int i = 0; i < 4; i++) {
        acc_i[i + 4][j] = __builtin_amdgcn_mfma_f32_16x16x32_bf16(a[i], bi[j], acc_i[i + 4][j], 0, 0, 0);
        acc_g[i + 4][j] = __builtin_amdgcn_mfma_f32_16x16x32_bf16(a[i], bg[j], acc_g[i + 4][j], 0, 0, 0);
      }
    __builtin_amdgcn_s_setprio(0);
    // counted drain: ensure kt+1 landed before next iteration reads it.
    // outstanding here: kt<=28 -> {kt+1,kt+2,kt+3}=12 -> vmcnt(8); kt==29 -> {30,31}=8 -> vmcnt(4);
    // kt==30 -> {31}=4 -> vmcnt(0); kt==31 -> none.
    if (kt <= NKT - 4)      { asm volatile("s_waitcnt vmcnt(8)" ::: "memory"); }
    else if (kt == NKT - 3) { asm volatile("s_waitcnt vmcnt(4)" ::: "memory"); }
    else if (kt == NKT - 2) { asm volatile("s_waitcnt vmcnt(0)" ::: "memory"); }
    block_barrier();
  }

  // ---- epilogue: GLU + store ----
  unsigned short* He = H + (size_t)e * CAP * IDIM;
#pragma unroll
  for (int i = 0; i < 8; i++) {
#pragma unroll
    for (int r = 0; r < 4; r++) {
      int m = m0 + wm + i * 16 + quad * 4 + r;
#pragma unroll
      for (int j = 0; j < 2; j++) {
        int n = i0 + wn + j * 16 + lane16;
        float vi = acc_i[i][j][r];
        float vg = acc_g[i][j][r];
        float h = 0.5f * vi * (1.0f + erff(vi * 0.70710678118654752f)) * vg;
        He[(size_t)m * IDIM + n] = f2b(h);
      }
    }
  }
}

// ---------------- GEMM2: full-K 128x128, gated scatter to out2[tok][slot] ----------------
// 2-deep counted-vmcnt pipeline (unchanged this round).
__global__ __launch_bounds__(256, 2) void gemm2_kernel(const unsigned short* __restrict__ H,
                                                       const unsigned short* __restrict__ w2t,
                                                       const int* __restrict__ cnt,
                                                       const int* __restrict__ rowtok,
                                                       const int* __restrict__ rowslot,
                                                       const float* __restrict__ rowgate,
                                                       float* __restrict__ out2) {
  int e  = blockIdx.z;
  int m0 = blockIdx.y * 128;
  int n0 = blockIdx.x * 128;
  int cnte = cnt[e];
  if (m0 >= cnte) return;

  __shared__ __align__(16) unsigned char smem[65536];  // 2 stages x 32 KB

  int tid  = threadIdx.x;
  int lane = tid & 63;
  int wave = tid >> 6;

  int sr0 = wave * 32 + (lane >> 2);
  int sr1 = sr0 + 16;
  int sk  = (lane & 3) * 8;

  const unsigned short* He  = H + (size_t)e * CAP * IDIM;
  const unsigned short* w2e = w2t + (size_t)e * DIM * IDIM;
  const unsigned short* gA0 = He + (size_t)(m0 + sr0) * IDIM + sk;
  const unsigned short* gA1 = He + (size_t)(m0 + sr1) * IDIM + sk;
  const unsigned short* gB0 = w2e + (size_t)(n0 + sr0) * IDIM + sk;
  const unsigned short* gB1 = w2e + (size_t)(n0 + sr1) * IDIM + sk;

  int lane16 = lane & 15;
  int quad   = lane >> 4;
  int wm = (wave & 1) * 64;
  int wn = (wave >> 1) * 64;

  auto stage = [&](int s, int k0) {
#pragma unroll
    for (int b = 0; b < 2; b++) {
      int kk = k0 + b * 32;
      unsigned short* A = (unsigned short*)(smem + s * 32768 + b * 8192);
      unsigned short* B = (unsigned short*)(smem + s * 32768 + 16384 + b * 8192);
      async16(gA0 + kk, A + (wave * 2 + 0) * 512);
      async16(gA1 + kk, A + (wave * 2 + 1) * 512);
      async16(gB0 + kk, B + (wave * 2 + 0) * 512);
      async16(gB1 + kk, B + (wave * 2 + 1) * 512);
    }
  };

  floatx4 acc[4][4];
#pragma unroll
  for (int i = 0; i < 4; i++)
#pragma unroll
    for (int j = 0; j < 4; j++) acc[i][j] = (floatx4){0.f, 0.f, 0.f, 0.f};

  const int T = IDIM / 64;  // 32
  stage(0, 0);
  stage(1, 64);
  for (int t = 0; t < T; ++t) {
    if (t < T - 1) asm volatile("s_waitcnt vmcnt(8)" ::: "memory");
    else           asm volatile("s_waitcnt vmcnt(0)" ::: "memory");
    block_barrier();

    int s = t & 1;
#pragma unroll
    for (int b = 0; b < 2; b++) {
      const unsigned short* Ab = (const unsigned short*)(smem + s * 32768 + b * 8192);
      const unsigned short* Bb = (const unsigned short*)(smem + s * 32768 + 16384 + b * 8192);
      short8 a[4];
#pragma unroll
      for (int i = 0; i < 4; i++)
        a[i] = *(const short8*)&Ab[(wm + i * 16 + lane16) * 32 + quad * 8];
#pragma unroll
      for (int j = 0; j < 4; j++) {
        short8 bb = *(const short8*)&Bb[(wn + j * 16 + lane16) * 32 + quad * 8];
#pragma unroll
        for (int i = 0; i < 4; i++)
          acc[i][j] = __builtin_amdgcn_mfma_f32_16x16x32_bf16(a[i], bb, acc[i][j], 0, 0, 0);
      }
    }

    block_barrier();
    if (t + 2 < T) stage(s, (t + 2) * 64);
  }

#pragma unroll
  for (int i = 0; i < 4; i++) {
#pragma unroll
    for (int r = 0; r < 4; r++) {
      int m = m0 + wm + i * 16 + quad * 4 + r;
      if (m < cnte) {
        int tok = rowtok[e * CAP + m];
        int sl  = rowslot[e * CAP + m];
        float g = rowgate[e * CAP + m];
        float* orow = out2 + ((size_t)tok * 2 + sl) * DIM;
#pragma unroll
        for (int j = 0; j < 4; j++) {
          int n = n0 + wn + j * 16 + lane16;
          orow[n] = g * acc[i][j][r];
        }
      }
    }
  }
}

// ---------------- combine: out[t] = sel(g0)*out2[t][0] + sel(g1)*out2[t][1] ----------------
__global__ __launch_bounds__(256) void combine_kernel(const float* __restrict__ tokgate,
                                                      const float* __restrict__ out2,
                                                      float* __restrict__ out) {
  int t = blockIdx.x;
  int tid = threadIdx.x;
  float g0 = tokgate[t * 2], g1 = tokgate[t * 2 + 1];
  const float4* r0 = reinterpret_cast<const float4*>(out2 + (size_t)(t * 2) * DIM);
  const float4* r1 = reinterpret_cast<const float4*>(out2 + (size_t)(t * 2 + 1) * DIM);
  float4 a = r0[tid], b = r1[tid];   // poison rows are finite; selected away below
  float4 o;
  o.x = (g0 != 0.0f ? a.x : 0.0f) + (g1 != 0.0f ? b.x : 0.0f);
  o.y = (g0 != 0.0f ? a.y : 0.0f) + (g1 != 0.0f ? b.y : 0.0f);
  o.z = (g0 != 0.0f ? a.z : 0.0f) + (g1 != 0.0f ? b.z : 0.0f);
  o.w = (g0 != 0.0f ? a.w : 0.0f) + (g1 != 0.0f ? b.w : 0.0f);
  reinterpret_cast<float4*>(out + (size_t)t * DIM)[tid] = o;
}

// ---------------- launch ----------------
extern "C" void kernel_launch(void* const* d_in, const int* in_sizes, int n_in,
                              void* d_out, int out_size, void* d_ws, size_t ws_size,
                              hipStream_t stream) {
  const float* x  = (const float*)d_in[0];
  const float* Wg = (const float*)d_in[1];
  const float* W1 = (const float*)d_in[2];
  const float* W2 = (const float*)d_in[3];
  float* out = (float*)d_out;

  char* ws = (char*)d_ws;
  size_t off = 0;
  auto alloc = [&](size_t bytes) -> void* {
    void* p = ws + off;
    off = (off + bytes + 255) & ~(size_t)255;
    return p;
  };
  int*   top_i   = (int*)alloc((size_t)N_TOK * 2 * sizeof(int));
  float* gates   = (float*)alloc((size_t)N_TOK * 2 * sizeof(float));
  int*   rowtok  = (int*)alloc((size_t)NEXP * CAP * sizeof(int));
  int*   rowslot = (int*)alloc((size_t)NEXP * CAP * sizeof(int));
  float* rowgate = (float*)alloc((size_t)NEXP * CAP * sizeof(float));
  float* tokgate = (float*)alloc((size_t)N_TOK * 2 * sizeof(float));
  int*   cnt     = (int*)alloc((size_t)NEXP * sizeof(int));
  unsigned short* xb  = (unsigned short*)alloc((size_t)N_TOK * DIM * 2);
  unsigned short* w1t = (unsigned short*)alloc((size_t)NEXP * TWOI * DIM * 2);
  unsigned short* w2t = (unsigned short*)alloc((size_t)NEXP * DIM * IDIM * 2);
  unsigned short* Hb  = (unsigned short*)alloc((size_t)NEXP * CAP * IDIM * 2);
  float* out2 = (float*)alloc((size_t)N_TOK * 2 * DIM * sizeof(float));
  if (off > ws_size) return;

  hipLaunchKernelGGL(prologue_kernel, dim3(W1_BLOCKS + ROUTER_BLOCKS), dim3(256), 0, stream,
                     W1, w1t, x, Wg, xb, top_i, gates);
  hipLaunchKernelGGL(scan_kernel, dim3(1), dim3(1024), 0, stream,
                     top_i, gates, rowtok, rowslot, rowgate, tokgate, cnt);
  hipLaunchKernelGGL(gemm1_kernel, dim3(G1X, G1Y, NEXP + G1_TRANS_Z), dim3(512), 0, stream,
                     xb, w1t, rowtok, cnt, Hb, W2, w2t);
  hipLaunchKernelGGL(gemm2_kernel, dim3(DIM / 128, CAP / 128, NEXP), dim3(256), 0, stream,
                     Hb, w2t, cnt, rowtok, rowslot, rowgate, out2);
  hipLaunchKernelGGL(combine_kernel, dim3(N_TOK), dim3(256), 0, stream,
                     tokgate, out2, out);
}

// Round 6
// 466.979 us; speedup vs baseline: 1.0004x; 1.0004x over previous
//
#include <hip/hip_runtime.h>
#include <hip/hip_bf16.h>
#include <math.h>

#define N_TOK 4096
#define DIM   1024
#define NEXP  8
#define IDIM  2048
#define TWOI  4096
#define CAP   1280

#define W1_BLOCKS (64 * 16 * NEXP)   // 8192 transpose tiles for W1
#define W2_BLOCKS (16 * 32 * NEXP)   // 4096 transpose tiles for W2
#define ROUTER_BLOCKS (N_TOK / 4)    // 1024

// gemm1 grid: x=32 n-tiles, y=10 m-tiles, z = 8 experts + 13 trans planes (320 blocks each)
#define G1X 32
#define G1Y 10
#define G1_TRANS_Z ((W2_BLOCKS + G1X * G1Y - 1) / (G1X * G1Y))  // 13

using short8  = __attribute__((ext_vector_type(8))) short;
using floatx4 = __attribute__((ext_vector_type(4))) float;

__device__ __forceinline__ unsigned short f2b(float f) {
  __hip_bfloat16 h = __float2bfloat16(f);
  return *reinterpret_cast<unsigned short*>(&h);
}

// async global->LDS, 16B per lane. LDS dst = wave-uniform base + lane*16.
__device__ __forceinline__ void async16(const unsigned short* g, unsigned short* l) {
  __builtin_amdgcn_global_load_lds(
      (const __attribute__((address_space(1))) unsigned int*)g,
      (__attribute__((address_space(3))) unsigned int*)l,
      16, 0, 0);
}

// ---------------- prologue: W1 transpose+convert AND router ----------------
__global__ __launch_bounds__(256) void prologue_kernel(const float* __restrict__ W1,
                                                       unsigned short* __restrict__ w1t,
                                                       const float* __restrict__ x,
                                                       const float* __restrict__ Wg,
                                                       unsigned short* __restrict__ xb,
                                                       int* __restrict__ top_i,
                                                       float* __restrict__ gates) {
  __shared__ __align__(16) float smem_f[NEXP * DIM];   // 32 KB, overlaid
  int bid = blockIdx.x;
  int tid = threadIdx.x;

  if (bid < W1_BLOCKS) {
    float (*tile)[65] = reinterpret_cast<float (*)[65]>(smem_f);
    int e = bid >> 10;
    int t = bid & 1023;
    const int R = DIM, C = TWOI;
    int r0 = (t & 15) * 64;
    int c0 = (t >> 4) * 64;
    const float* s = W1 + (size_t)e * R * C;
    unsigned short* d = w1t + (size_t)e * R * C;
    int tr = tid >> 4, tc = (tid & 15) * 4;
#pragma unroll
    for (int i = 0; i < 4; i++) {
      float4 v = *reinterpret_cast<const float4*>(&s[(size_t)(r0 + tr + i * 16) * C + c0 + tc]);
      tile[tr + i * 16][tc]     = v.x;
      tile[tr + i * 16][tc + 1] = v.y;
      tile[tr + i * 16][tc + 2] = v.z;
      tile[tr + i * 16][tc + 3] = v.w;
    }
    __syncthreads();
#pragma unroll
    for (int j = 0; j < 4; j++) {
      int c = (tid >> 4) + j * 16;
      int r4 = (tid & 15) * 4;
      ushort4 o;
      o.x = f2b(tile[r4][c]);
      o.y = f2b(tile[r4 + 1][c]);
      o.z = f2b(tile[r4 + 2][c]);
      o.w = f2b(tile[r4 + 3][c]);
      *reinterpret_cast<ushort4*>(&d[(size_t)(c0 + c) * R + r0 + r4]) = o;
    }
  } else {
    int rb = bid - W1_BLOCKS;
    float* wg = smem_f;
    for (int i = tid * 4; i < NEXP * DIM; i += 256 * 4) {
      *reinterpret_cast<float4*>(wg + i) = *reinterpret_cast<const float4*>(Wg + i);
    }
    __syncthreads();
    int wave = tid >> 6, lane = tid & 63;
    int t = rb * 4 + wave;
    const float* xr = x + (size_t)t * DIM;
    unsigned short* xbr = xb + (size_t)t * DIM;
    double acc[NEXP];
#pragma unroll
    for (int e = 0; e < NEXP; e++) acc[e] = 0.0;
    for (int i = lane; i < DIM; i += 64) {
      float xf = xr[i];
      xbr[i] = f2b(xf);
      double xv = (double)xf;
#pragma unroll
      for (int e = 0; e < NEXP; e++) acc[e] += xv * (double)wg[e * DIM + i];
    }
#pragma unroll
    for (int e = 0; e < NEXP; e++) {
#pragma unroll
      for (int m = 1; m < 64; m <<= 1) acc[e] += __shfl_xor(acc[e], m, 64);
    }
    if (lane == 0) {
      int i0 = 0; double v0 = acc[0];
      for (int e = 1; e < NEXP; e++) { if (acc[e] > v0) { v0 = acc[e]; i0 = e; } }
      int i1 = -1; double v1 = -1e300;
      for (int e = 0; e < NEXP; e++) { if (e != i0 && acc[e] > v1) { v1 = acc[e]; i1 = e; } }
      double e1 = exp(v1 - v0);
      float g0 = (float)(1.0 / (1.0 + e1));
      float g1 = (float)(e1 / (1.0 + e1));
      top_i[t * 2] = i0; top_i[t * 2 + 1] = i1;
      gates[t * 2] = g0; gates[t * 2 + 1] = g1;
    }
  }
}

// ---------------- capacity scan (deterministic, token-major slot order) ----------------
__global__ __launch_bounds__(1024) void scan_kernel(const int* __restrict__ top_i,
                                                    const float* __restrict__ gates,
                                                    int* __restrict__ rowtok,
                                                    int* __restrict__ rowslot,
                                                    float* __restrict__ rowgate,
                                                    float* __restrict__ tokgate,
                                                    int* __restrict__ cnt) {
  __shared__ int hist[NEXP][1024];
  int t = threadIdx.x;
  int s0 = t * 8;
  int eloc[8];
  int c[NEXP];
#pragma unroll
  for (int e = 0; e < NEXP; e++) c[e] = 0;
#pragma unroll
  for (int j = 0; j < 8; j++) { int e = top_i[s0 + j]; eloc[j] = e; c[e]++; }
#pragma unroll
  for (int e = 0; e < NEXP; e++) hist[e][t] = c[e];
  __syncthreads();
  for (int step = 1; step < 1024; step <<= 1) {
    int tmp[NEXP];
#pragma unroll
    for (int e = 0; e < NEXP; e++) tmp[e] = (t >= step) ? hist[e][t - step] : 0;
    __syncthreads();
#pragma unroll
    for (int e = 0; e < NEXP; e++) hist[e][t] += tmp[e];
    __syncthreads();
  }
  int base[NEXP];
#pragma unroll
  for (int e = 0; e < NEXP; e++) base[e] = hist[e][t] - c[e];
  if (t < NEXP) {
    int tot = hist[t][1023];
    cnt[t] = tot < CAP ? tot : CAP;
  }
#pragma unroll
  for (int j = 0; j < 8; j++) {
    int s = s0 + j;
    int e = eloc[j];
    int pos = base[e]++;
    bool keep = pos < CAP;
    tokgate[s] = keep ? gates[s] : 0.0f;   // 0 marks a dropped slot (real gates are > 0)
    if (keep) {
      rowtok[e * CAP + pos]  = s >> 1;
      rowslot[e * CAP + pos] = s & 1;
      rowgate[e * CAP + pos] = gates[s];
    }
  }
}

// ---------------- GEMM1 + GLU (z<8)  |  W2 transpose (z>=8) ----------------
// Reverted to 32 KB single-stage structure (5 blocks/CU; cross-block TLP covers the
// syncthreads drain, m114/m97 mechanism). Added: XCD-aware tile swizzle (T1).
__global__ __launch_bounds__(256, 4) void gemm1_kernel(const unsigned short* __restrict__ xb,
                                                       const unsigned short* __restrict__ w1t,
                                                       const int* __restrict__ rowtok,
                                                       const int* __restrict__ cnt,
                                                       unsigned short* __restrict__ H,
                                                       const float* __restrict__ W2,
                                                       unsigned short* __restrict__ w2t) {
  __shared__ __align__(16) unsigned char smem[32768];  // gemm: 32 KB; trans overlay: 16.6 KB
  int tid  = threadIdx.x;
  int z = blockIdx.z;

  if (z >= NEXP) {
    // ---- W2 transpose plane ----
    int id = (z - NEXP) * (G1X * G1Y) + blockIdx.y * G1X + blockIdx.x;
    if (id >= W2_BLOCKS) return;
    float (*tile)[65] = reinterpret_cast<float (*)[65]>(smem);
    int e = id >> 9;
    int t = id & 511;
    const int R = IDIM, C = DIM;
    int r0 = (t & 31) * 64;
    int c0 = (t >> 5) * 64;
    const float* s = W2 + (size_t)e * R * C;
    unsigned short* d = w2t + (size_t)e * R * C;
    int tr = tid >> 4, tc = (tid & 15) * 4;
#pragma unroll
    for (int i = 0; i < 4; i++) {
      float4 v = *reinterpret_cast<const float4*>(&s[(size_t)(r0 + tr + i * 16) * C + c0 + tc]);
      tile[tr + i * 16][tc]     = v.x;
      tile[tr + i * 16][tc + 1] = v.y;
      tile[tr + i * 16][tc + 2] = v.z;
      tile[tr + i * 16][tc + 3] = v.w;
    }
    __syncthreads();
#pragma unroll
    for (int j = 0; j < 4; j++) {
      int c = (tid >> 4) + j * 16;
      int r4 = (tid & 15) * 4;
      ushort4 o;
      o.x = f2b(tile[r4][c]);
      o.y = f2b(tile[r4 + 1][c]);
      o.z = f2b(tile[r4 + 2][c]);
      o.w = f2b(tile[r4 + 3][c]);
      *reinterpret_cast<ushort4*>(&d[(size_t)(c0 + c) * R + r0 + r4]) = o;
    }
    return;
  }

  // ---- gemm1 path ----
  int e  = z;
  // T1 XCD swizzle: dispatch id round-robins XCDs; remap so one XCD covers one m-panel's
  // n-sweep (A-panel stays hot in that XCD's L2 across its 32 restagings). 320 % 8 == 0.
  int lin = blockIdx.y * G1X + blockIdx.x;          // 0..319
  int swz = (lin & 7) * (G1X * G1Y / 8) + (lin >> 3);
  int m0 = (swz / G1X) * 128;
  int i0 = (swz % G1X) * 64;
  int cnte = cnt[e];
  if (m0 >= cnte) return;

  unsigned short* As[2] = { (unsigned short*)smem,           (unsigned short*)(smem + 8192) };
  unsigned short* Bi[2] = { (unsigned short*)(smem + 16384), (unsigned short*)(smem + 20480) };
  unsigned short* Bg[2] = { (unsigned short*)(smem + 24576), (unsigned short*)(smem + 28672) };

  int lane = tid & 63;
  int wave = tid >> 6;

  int srA0 = wave * 32 + (lane >> 2);
  int srA1 = srA0 + 16;
  int srB  = wave * 16 + (lane >> 2);
  int sk   = (lane & 3) * 8;

  int ma0 = m0 + srA0, ma1 = m0 + srA1;
  int tok0 = (ma0 < cnte) ? rowtok[e * CAP + ma0] : 0;
  int tok1 = (ma1 < cnte) ? rowtok[e * CAP + ma1] : 0;

  const unsigned short* w1e = w1t + (size_t)e * TWOI * DIM;
  const unsigned short* gA0 = xb + (size_t)tok0 * DIM + sk;
  const unsigned short* gA1 = xb + (size_t)tok1 * DIM + sk;
  const unsigned short* gBi = w1e + (size_t)(i0 + srB) * DIM + sk;
  const unsigned short* gBg = w1e + (size_t)(i0 + srB + IDIM) * DIM + sk;

  int lane16 = lane & 15;
  int quad   = lane >> 4;
  int wm = (wave & 1) * 64;
  int wn = (wave >> 1) * 32;

  floatx4 acc_i[4][2], acc_g[4][2];
#pragma unroll
  for (int i = 0; i < 4; i++)
#pragma unroll
    for (int j = 0; j < 2; j++) {
      acc_i[i][j] = (floatx4){0.f, 0.f, 0.f, 0.f};
      acc_g[i][j] = (floatx4){0.f, 0.f, 0.f, 0.f};
    }

  for (int k0 = 0; k0 < DIM; k0 += 64) {
    __syncthreads();
#pragma unroll
    for (int b = 0; b < 2; b++) {
      int kk = k0 + b * 32;
      async16(gA0 + kk, As[b] + (wave * 2 + 0) * 512);
      async16(gA1 + kk, As[b] + (wave * 2 + 1) * 512);
      async16(gBi + kk, Bi[b] + wave * 512);
      async16(gBg + kk, Bg[b] + wave * 512);
    }
    __syncthreads();

#pragma unroll
    for (int b = 0; b < 2; b++) {
      short8 a[4];
#pragma unroll
      for (int i = 0; i < 4; i++)
        a[i] = *(const short8*)&As[b][(wm + i * 16 + lane16) * 32 + quad * 8];
#pragma unroll
      for (int j = 0; j < 2; j++) {
        short8 bi = *(const short8*)&Bi[b][(wn + j * 16 + lane16) * 32 + quad * 8];
#pragma unroll
        for (int i = 0; i < 4; i++)
          acc_i[i][j] = __builtin_amdgcn_mfma_f32_16x16x32_bf16(a[i], bi, acc_i[i][j], 0, 0, 0);
        short8 bg = *(const short8*)&Bg[b][(wn + j * 16 + lane16) * 32 + quad * 8];
#pragma unroll
        for (int i = 0; i < 4; i++)
          acc_g[i][j] = __builtin_amdgcn_mfma_f32_16x16x32_bf16(a[i], bg, acc_g[i][j], 0, 0, 0);
      }
    }
  }

  unsigned short* He = H + (size_t)e * CAP * IDIM;
#pragma unroll
  for (int i = 0; i < 4; i++) {
#pragma unroll
    for (int r = 0; r < 4; r++) {
      int m = m0 + wm + i * 16 + quad * 4 + r;
#pragma unroll
      for (int j = 0; j < 2; j++) {
        int n = i0 + wn + j * 16 + lane16;
        float vi = acc_i[i][j][r];
        float vg = acc_g[i][j][r];
        float h = 0.5f * vi * (1.0f + erff(vi * 0.70710678118654752f)) * vg;
        He[(size_t)m * IDIM + n] = f2b(h);
      }
    }
  }
}

// ---------------- GEMM2: full-K 128x128, gated scatter to out2[tok][slot] ----------------
// Reverted to 32 KB single-stage structure + XCD swizzle.
__global__ __launch_bounds__(256, 4) void gemm2_kernel(const unsigned short* __restrict__ H,
                                                       const unsigned short* __restrict__ w2t,
                                                       const int* __restrict__ cnt,
                                                       const int* __restrict__ rowtok,
                                                       const int* __restrict__ rowslot,
                                                       const float* __restrict__ rowgate,
                                                       float* __restrict__ out2) {
  int e  = blockIdx.z;
  // T1 XCD swizzle within the 80-block plane (80 % 8 == 0): one XCD covers ~one m-panel.
  int lin = blockIdx.y * 8 + blockIdx.x;   // 0..79
  int swz = (lin & 7) * 10 + (lin >> 3);
  int m0 = (swz / 8) * 128;
  int n0 = (swz % 8) * 128;
  int cnte = cnt[e];
  if (m0 >= cnte) return;

  __shared__ __align__(16) unsigned char smem[32768];
  unsigned short* As[2] = { (unsigned short*)smem,           (unsigned short*)(smem + 8192) };
  unsigned short* Bs[2] = { (unsigned short*)(smem + 16384), (unsigned short*)(smem + 24576) };

  int tid  = threadIdx.x;
  int lane = tid & 63;
  int wave = tid >> 6;

  int sr0 = wave * 32 + (lane >> 2);
  int sr1 = sr0 + 16;
  int sk  = (lane & 3) * 8;

  const unsigned short* He  = H + (size_t)e * CAP * IDIM;
  const unsigned short* w2e = w2t + (size_t)e * DIM * IDIM;
  const unsigned short* gA0 = He + (size_t)(m0 + sr0) * IDIM + sk;
  const unsigned short* gA1 = He + (size_t)(m0 + sr1) * IDIM + sk;
  const unsigned short* gB0 = w2e + (size_t)(n0 + sr0) * IDIM + sk;
  const unsigned short* gB1 = w2e + (size_t)(n0 + sr1) * IDIM + sk;

  int lane16 = lane & 15;
  int quad   = lane >> 4;
  int wm = (wave & 1) * 64;
  int wn = (wave >> 1) * 64;

  floatx4 acc[4][4];
#pragma unroll
  for (int i = 0; i < 4; i++)
#pragma unroll
    for (int j = 0; j < 4; j++) acc[i][j] = (floatx4){0.f, 0.f, 0.f, 0.f};

  for (int k0 = 0; k0 < IDIM; k0 += 64) {
    __syncthreads();
#pragma unroll
    for (int b = 0; b < 2; b++) {
      int kk = k0 + b * 32;
      async16(gA0 + kk, As[b] + (wave * 2 + 0) * 512);
      async16(gA1 + kk, As[b] + (wave * 2 + 1) * 512);
      async16(gB0 + kk, Bs[b] + (wave * 2 + 0) * 512);
      async16(gB1 + kk, Bs[b] + (wave * 2 + 1) * 512);
    }
    __syncthreads();

#pragma unroll
    for (int b = 0; b < 2; b++) {
      short8 a[4];
#pragma unroll
      for (int i = 0; i < 4; i++)
        a[i] = *(const short8*)&As[b][(wm + i * 16 + lane16) * 32 + quad * 8];
#pragma unroll
      for (int j = 0; j < 4; j++) {
        short8 bb = *(const short8*)&Bs[b][(wn + j * 16 + lane16) * 32 + quad * 8];
#pragma unroll
        for (int i = 0; i < 4; i++)
          acc[i][j] = __builtin_amdgcn_mfma_f32_16x16x32_bf16(a[i], bb, acc[i][j], 0, 0, 0);
      }
    }
  }

#pragma unroll
  for (int i = 0; i < 4; i++) {
#pragma unroll
    for (int r = 0; r < 4; r++) {
      int m = m0 + wm + i * 16 + quad * 4 + r;
      if (m < cnte) {
        int tok = rowtok[e * CAP + m];
        int sl  = rowslot[e * CAP + m];
        float g = rowgate[e * CAP + m];
        float* orow = out2 + ((size_t)tok * 2 + sl) * DIM;
#pragma unroll
        for (int j = 0; j < 4; j++) {
          int n = n0 + wn + j * 16 + lane16;
          orow[n] = g * acc[i][j][r];
        }
      }
    }
  }
}

// ---------------- combine: out[t] = sel(g0)*out2[t][0] + sel(g1)*out2[t][1] ----------------
__global__ __launch_bounds__(256) void combine_kernel(const float* __restrict__ tokgate,
                                                      const float* __restrict__ out2,
                                                      float* __restrict__ out) {
  int t = blockIdx.x;
  int tid = threadIdx.x;
  float g0 = tokgate[t * 2], g1 = tokgate[t * 2 + 1];
  const float4* r0 = reinterpret_cast<const float4*>(out2 + (size_t)(t * 2) * DIM);
  const float4* r1 = reinterpret_cast<const float4*>(out2 + (size_t)(t * 2 + 1) * DIM);
  float4 a = r0[tid], b = r1[tid];   // poison rows are finite; selected away below
  float4 o;
  o.x = (g0 != 0.0f ? a.x : 0.0f) + (g1 != 0.0f ? b.x : 0.0f);
  o.y = (g0 != 0.0f ? a.y : 0.0f) + (g1 != 0.0f ? b.y : 0.0f);
  o.z = (g0 != 0.0f ? a.z : 0.0f) + (g1 != 0.0f ? b.z : 0.0f);
  o.w = (g0 != 0.0f ? a.w : 0.0f) + (g1 != 0.0f ? b.w : 0.0f);
  reinterpret_cast<float4*>(out + (size_t)t * DIM)[tid] = o;
}

// ---------------- launch ----------------
extern "C" void kernel_launch(void* const* d_in, const int* in_sizes, int n_in,
                              void* d_out, int out_size, void* d_ws, size_t ws_size,
                              hipStream_t stream) {
  const float* x  = (const float*)d_in[0];
  const float* Wg = (const float*)d_in[1];
  const float* W1 = (const float*)d_in[2];
  const float* W2 = (const float*)d_in[3];
  float* out = (float*)d_out;

  char* ws = (char*)d_ws;
  size_t off = 0;
  auto alloc = [&](size_t bytes) -> void* {
    void* p = ws + off;
    off = (off + bytes + 255) & ~(size_t)255;
    return p;
  };
  int*   top_i   = (int*)alloc((size_t)N_TOK * 2 * sizeof(int));
  float* gates   = (float*)alloc((size_t)N_TOK * 2 * sizeof(float));
  int*   rowtok  = (int*)alloc((size_t)NEXP * CAP * sizeof(int));
  int*   rowslot = (int*)alloc((size_t)NEXP * CAP * sizeof(int));
  float* rowgate = (float*)alloc((size_t)NEXP * CAP * sizeof(float));
  float* tokgate = (float*)alloc((size_t)N_TOK * 2 * sizeof(float));
  int*   cnt     = (int*)alloc((size_t)NEXP * sizeof(int));
  unsigned short* xb  = (unsigned short*)alloc((size_t)N_TOK * DIM * 2);
  unsigned short* w1t = (unsigned short*)alloc((size_t)NEXP * TWOI * DIM * 2);
  unsigned short* w2t = (unsigned short*)alloc((size_t)NEXP * DIM * IDIM * 2);
  unsigned short* Hb  = (unsigned short*)alloc((size_t)NEXP * CAP * IDIM * 2);
  float* out2 = (float*)alloc((size_t)N_TOK * 2 * DIM * sizeof(float));
  if (off > ws_size) return;

  hipLaunchKernelGGL(prologue_kernel, dim3(W1_BLOCKS + ROUTER_BLOCKS), dim3(256), 0, stream,
                     W1, w1t, x, Wg, xb, top_i, gates);
  hipLaunchKernelGGL(scan_kernel, dim3(1), dim3(1024), 0, stream,
                     top_i, gates, rowtok, rowslot, rowgate, tokgate, cnt);
  hipLaunchKernelGGL(gemm1_kernel, dim3(G1X, G1Y, NEXP + G1_TRANS_Z), dim3(256), 0, stream,
                     xb, w1t, rowtok, cnt, Hb, W2, w2t);
  hipLaunchKernelGGL(gemm2_kernel, dim3(DIM / 128, CAP / 128, NEXP), dim3(256), 0, stream,
                     Hb, w2t, cnt, rowtok, rowslot, rowgate, out2);
  hipLaunchKernelGGL(combine_kernel, dim3(N_TOK), dim3(256), 0, stream,
                     tokgate, out2, out);
}

// Round 8
// 438.496 us; speedup vs baseline: 1.0653x; 1.0650x over previous
//
#include <hip/hip_runtime.h>
#include <hip/hip_bf16.h>
#include <math.h>

#define N_TOK 4096
#define DIM   1024
#define NEXP  8
#define IDIM  2048
#define TWOI  4096
#define CAP   1280

#define W1_BLOCKS (64 * 16 * NEXP)   // 8192 transpose tiles for W1
#define W2_BLOCKS (16 * 32 * NEXP)   // 4096 transpose tiles for W2
#define ROUTER_BLOCKS (N_TOK / 4)    // 1024

// gemm1 grid: x=32 n-tiles, y=10 m-tiles, z = 8 experts + 13 trans planes (320 blocks each)
#define G1X 32
#define G1Y 10
#define G1_TRANS_Z ((W2_BLOCKS + G1X * G1Y - 1) / (G1X * G1Y))  // 13

using short8  = __attribute__((ext_vector_type(8))) short;
using floatx4 = __attribute__((ext_vector_type(4))) float;

__device__ __forceinline__ unsigned short f2b(float f) {
  __hip_bfloat16 h = __float2bfloat16(f);
  return *reinterpret_cast<unsigned short*>(&h);
}

// async global->LDS, 16B per lane. LDS dst = wave-uniform base + lane*16.
__device__ __forceinline__ void async16(const unsigned short* g, unsigned short* l) {
  __builtin_amdgcn_global_load_lds(
      (const __attribute__((address_space(1))) unsigned int*)g,
      (__attribute__((address_space(3))) unsigned int*)l,
      16, 0, 0);
}

// ---------------- prologue: W1 transpose+convert AND router (+ zero out) ----------------
__global__ __launch_bounds__(256) void prologue_kernel(const float* __restrict__ W1,
                                                       unsigned short* __restrict__ w1t,
                                                       const float* __restrict__ x,
                                                       const float* __restrict__ Wg,
                                                       unsigned short* __restrict__ xb,
                                                       int* __restrict__ top_i,
                                                       float* __restrict__ gates,
                                                       float* __restrict__ out) {
  __shared__ __align__(16) float smem_f[NEXP * DIM];   // 32 KB, overlaid
  int bid = blockIdx.x;
  int tid = threadIdx.x;

  if (bid < W1_BLOCKS) {
    float (*tile)[65] = reinterpret_cast<float (*)[65]>(smem_f);
    int e = bid >> 10;
    int t = bid & 1023;
    const int R = DIM, C = TWOI;
    int r0 = (t & 15) * 64;
    int c0 = (t >> 4) * 64;
    const float* s = W1 + (size_t)e * R * C;
    unsigned short* d = w1t + (size_t)e * R * C;
    int tr = tid >> 4, tc = (tid & 15) * 4;
#pragma unroll
    for (int i = 0; i < 4; i++) {
      float4 v = *reinterpret_cast<const float4*>(&s[(size_t)(r0 + tr + i * 16) * C + c0 + tc]);
      tile[tr + i * 16][tc]     = v.x;
      tile[tr + i * 16][tc + 1] = v.y;
      tile[tr + i * 16][tc + 2] = v.z;
      tile[tr + i * 16][tc + 3] = v.w;
    }
    __syncthreads();
#pragma unroll
    for (int j = 0; j < 4; j++) {
      int c = (tid >> 4) + j * 16;
      int r4 = (tid & 15) * 4;
      ushort4 o;
      o.x = f2b(tile[r4][c]);
      o.y = f2b(tile[r4 + 1][c]);
      o.z = f2b(tile[r4 + 2][c]);
      o.w = f2b(tile[r4 + 3][c]);
      *reinterpret_cast<ushort4*>(&d[(size_t)(c0 + c) * R + r0 + r4]) = o;
    }
  } else {
    int rb = bid - W1_BLOCKS;
    // zero the output rows for this block's 4 tokens (gemm2 accumulates atomically)
    {
      float4 z4 = {0.f, 0.f, 0.f, 0.f};
      float4* ob = reinterpret_cast<float4*>(out + (size_t)rb * 4 * DIM);
#pragma unroll
      for (int i = 0; i < 4; i++) ob[tid + i * 256] = z4;
    }
    float* wg = smem_f;
    for (int i = tid * 4; i < NEXP * DIM; i += 256 * 4) {
      *reinterpret_cast<float4*>(wg + i) = *reinterpret_cast<const float4*>(Wg + i);
    }
    __syncthreads();
    int wave = tid >> 6, lane = tid & 63;
    int t = rb * 4 + wave;
    const float* xr = x + (size_t)t * DIM;
    unsigned short* xbr = xb + (size_t)t * DIM;
    double acc[NEXP];
#pragma unroll
    for (int e = 0; e < NEXP; e++) acc[e] = 0.0;
    for (int i = lane; i < DIM; i += 64) {
      float xf = xr[i];
      xbr[i] = f2b(xf);
      double xv = (double)xf;
#pragma unroll
      for (int e = 0; e < NEXP; e++) acc[e] += xv * (double)wg[e * DIM + i];
    }
#pragma unroll
    for (int e = 0; e < NEXP; e++) {
#pragma unroll
      for (int m = 1; m < 64; m <<= 1) acc[e] += __shfl_xor(acc[e], m, 64);
    }
    if (lane == 0) {
      int i0 = 0; double v0 = acc[0];
      for (int e = 1; e < NEXP; e++) { if (acc[e] > v0) { v0 = acc[e]; i0 = e; } }
      int i1 = -1; double v1 = -1e300;
      for (int e = 0; e < NEXP; e++) { if (e != i0 && acc[e] > v1) { v1 = acc[e]; i1 = e; } }
      double e1 = exp(v1 - v0);
      float g0 = (float)(1.0 / (1.0 + e1));
      float g1 = (float)(e1 / (1.0 + e1));
      top_i[t * 2] = i0; top_i[t * 2 + 1] = i1;
      gates[t * 2] = g0; gates[t * 2 + 1] = g1;
    }
  }
}

// ---------------- capacity scan (deterministic, token-major slot order) ----------------
__global__ __launch_bounds__(1024) void scan_kernel(const int* __restrict__ top_i,
                                                    const float* __restrict__ gates,
                                                    int* __restrict__ rowtok,
                                                    float* __restrict__ rowgate,
                                                    int* __restrict__ cnt) {
  __shared__ int hist[NEXP][1024];
  int t = threadIdx.x;
  int s0 = t * 8;
  int eloc[8];
  int c[NEXP];
#pragma unroll
  for (int e = 0; e < NEXP; e++) c[e] = 0;
#pragma unroll
  for (int j = 0; j < 8; j++) { int e = top_i[s0 + j]; eloc[j] = e; c[e]++; }
#pragma unroll
  for (int e = 0; e < NEXP; e++) hist[e][t] = c[e];
  __syncthreads();
  for (int step = 1; step < 1024; step <<= 1) {
    int tmp[NEXP];
#pragma unroll
    for (int e = 0; e < NEXP; e++) tmp[e] = (t >= step) ? hist[e][t - step] : 0;
    __syncthreads();
#pragma unroll
    for (int e = 0; e < NEXP; e++) hist[e][t] += tmp[e];
    __syncthreads();
  }
  int base[NEXP];
#pragma unroll
  for (int e = 0; e < NEXP; e++) base[e] = hist[e][t] - c[e];
  if (t < NEXP) {
    int tot = hist[t][1023];
    cnt[t] = tot < CAP ? tot : CAP;
  }
#pragma unroll
  for (int j = 0; j < 8; j++) {
    int s = s0 + j;
    int e = eloc[j];
    int pos = base[e]++;
    if (pos < CAP) {
      rowtok[e * CAP + pos]  = s >> 1;   // token id (dropped slots never recorded)
      rowgate[e * CAP + pos] = gates[s];
    }
  }
}

// ---------------- GEMM1 + GLU (z<8)  |  W2 transpose (z>=8) ----------------
// 32 KB single-stage structure, natural dispatch order (5 blocks/CU; cross-block TLP
// covers the syncthreads drain — m114/m97 mechanism; XCD swizzle refuted in R6: 2x FETCH).
__global__ __launch_bounds__(256, 4) void gemm1_kernel(const unsigned short* __restrict__ xb,
                                                       const unsigned short* __restrict__ w1t,
                                                       const int* __restrict__ rowtok,
                                                       const int* __restrict__ cnt,
                                                       unsigned short* __restrict__ H,
                                                       const float* __restrict__ W2,
                                                       unsigned short* __restrict__ w2t) {
  __shared__ __align__(16) unsigned char smem[32768];  // gemm: 32 KB; trans overlay: 16.6 KB
  int tid  = threadIdx.x;
  int z = blockIdx.z;

  if (z >= NEXP) {
    // ---- W2 transpose plane ----
    int id = (z - NEXP) * (G1X * G1Y) + blockIdx.y * G1X + blockIdx.x;
    if (id >= W2_BLOCKS) return;
    float (*tile)[65] = reinterpret_cast<float (*)[65]>(smem);
    int e = id >> 9;
    int t = id & 511;
    const int R = IDIM, C = DIM;
    int r0 = (t & 31) * 64;
    int c0 = (t >> 5) * 64;
    const float* s = W2 + (size_t)e * R * C;
    unsigned short* d = w2t + (size_t)e * R * C;
    int tr = tid >> 4, tc = (tid & 15) * 4;
#pragma unroll
    for (int i = 0; i < 4; i++) {
      float4 v = *reinterpret_cast<const float4*>(&s[(size_t)(r0 + tr + i * 16) * C + c0 + tc]);
      tile[tr + i * 16][tc]     = v.x;
      tile[tr + i * 16][tc + 1] = v.y;
      tile[tr + i * 16][tc + 2] = v.z;
      tile[tr + i * 16][tc + 3] = v.w;
    }
    __syncthreads();
#pragma unroll
    for (int j = 0; j < 4; j++) {
      int c = (tid >> 4) + j * 16;
      int r4 = (tid & 15) * 4;
      ushort4 o;
      o.x = f2b(tile[r4][c]);
      o.y = f2b(tile[r4 + 1][c]);
      o.z = f2b(tile[r4 + 2][c]);
      o.w = f2b(tile[r4 + 3][c]);
      *reinterpret_cast<ushort4*>(&d[(size_t)(c0 + c) * R + r0 + r4]) = o;
    }
    return;
  }

  // ---- gemm1 path (natural order: consecutive blocks share the A-panel) ----
  int e  = z;
  int m0 = blockIdx.y * 128;
  int i0 = blockIdx.x * 64;
  int cnte = cnt[e];
  if (m0 >= cnte) return;

  unsigned short* As[2] = { (unsigned short*)smem,           (unsigned short*)(smem + 8192) };
  unsigned short* Bi[2] = { (unsigned short*)(smem + 16384), (unsigned short*)(smem + 20480) };
  unsigned short* Bg[2] = { (unsigned short*)(smem + 24576), (unsigned short*)(smem + 28672) };

  int lane = tid & 63;
  int wave = tid >> 6;

  int srA0 = wave * 32 + (lane >> 2);
  int srA1 = srA0 + 16;
  int srB  = wave * 16 + (lane >> 2);
  int sk   = (lane & 3) * 8;

  int ma0 = m0 + srA0, ma1 = m0 + srA1;
  int tok0 = (ma0 < cnte) ? rowtok[e * CAP + ma0] : 0;
  int tok1 = (ma1 < cnte) ? rowtok[e * CAP + ma1] : 0;

  const unsigned short* w1e = w1t + (size_t)e * TWOI * DIM;
  const unsigned short* gA0 = xb + (size_t)tok0 * DIM + sk;
  const unsigned short* gA1 = xb + (size_t)tok1 * DIM + sk;
  const unsigned short* gBi = w1e + (size_t)(i0 + srB) * DIM + sk;
  const unsigned short* gBg = w1e + (size_t)(i0 + srB + IDIM) * DIM + sk;

  int lane16 = lane & 15;
  int quad   = lane >> 4;
  int wm = (wave & 1) * 64;
  int wn = (wave >> 1) * 32;

  floatx4 acc_i[4][2], acc_g[4][2];
#pragma unroll
  for (int i = 0; i < 4; i++)
#pragma unroll
    for (int j = 0; j < 2; j++) {
      acc_i[i][j] = (floatx4){0.f, 0.f, 0.f, 0.f};
      acc_g[i][j] = (floatx4){0.f, 0.f, 0.f, 0.f};
    }

  for (int k0 = 0; k0 < DIM; k0 += 64) {
    __syncthreads();
#pragma unroll
    for (int b = 0; b < 2; b++) {
      int kk = k0 + b * 32;
      async16(gA0 + kk, As[b] + (wave * 2 + 0) * 512);
      async16(gA1 + kk, As[b] + (wave * 2 + 1) * 512);
      async16(gBi + kk, Bi[b] + wave * 512);
      async16(gBg + kk, Bg[b] + wave * 512);
    }
    __syncthreads();

#pragma unroll
    for (int b = 0; b < 2; b++) {
      short8 a[4];
#pragma unroll
      for (int i = 0; i < 4; i++)
        a[i] = *(const short8*)&As[b][(wm + i * 16 + lane16) * 32 + quad * 8];
#pragma unroll
      for (int j = 0; j < 2; j++) {
        short8 bi = *(const short8*)&Bi[b][(wn + j * 16 + lane16) * 32 + quad * 8];
#pragma unroll
        for (int i = 0; i < 4; i++)
          acc_i[i][j] = __builtin_amdgcn_mfma_f32_16x16x32_bf16(a[i], bi, acc_i[i][j], 0, 0, 0);
        short8 bg = *(const short8*)&Bg[b][(wn + j * 16 + lane16) * 32 + quad * 8];
#pragma unroll
        for (int i = 0; i < 4; i++)
          acc_g[i][j] = __builtin_amdgcn_mfma_f32_16x16x32_bf16(a[i], bg, acc_g[i][j], 0, 0, 0);
      }
    }
  }

  unsigned short* He = H + (size_t)e * CAP * IDIM;
#pragma unroll
  for (int i = 0; i < 4; i++) {
#pragma unroll
    for (int r = 0; r < 4; r++) {
      int m = m0 + wm + i * 16 + quad * 4 + r;
#pragma unroll
      for (int j = 0; j < 2; j++) {
        int n = i0 + wn + j * 16 + lane16;
        float vi = acc_i[i][j][r];
        float vg = acc_g[i][j][r];
        float h = 0.5f * vi * (1.0f + erff(vi * 0.70710678118654752f)) * vg;
        He[(size_t)m * IDIM + n] = f2b(h);
      }
    }
  }
}

// ---------------- GEMM2: full-K 128x128, gated atomic accumulate into out ----------------
// Combine fused: out[tok] += g * acc (<=2 contributors/row; 2-term fp32 add is
// order-independent; out zeroed by prologue).
__global__ __launch_bounds__(256, 4) void gemm2_kernel(const unsigned short* __restrict__ H,
                                                       const unsigned short* __restrict__ w2t,
                                                       const int* __restrict__ cnt,
                                                       const int* __restrict__ rowtok,
                                                       const float* __restrict__ rowgate,
                                                       float* __restrict__ out) {
  int e  = blockIdx.z;
  int m0 = blockIdx.y * 128;
  int n0 = blockIdx.x * 128;
  int cnte = cnt[e];
  if (m0 >= cnte) return;

  __shared__ __align__(16) unsigned char smem[32768];
  unsigned short* As[2] = { (unsigned short*)smem,           (unsigned short*)(smem + 8192) };
  unsigned short* Bs[2] = { (unsigned short*)(smem + 16384), (unsigned short*)(smem + 24576) };

  int tid  = threadIdx.x;
  int lane = tid & 63;
  int wave = tid >> 6;

  int sr0 = wave * 32 + (lane >> 2);
  int sr1 = sr0 + 16;
  int sk  = (lane & 3) * 8;

  const unsigned short* He  = H + (size_t)e * CAP * IDIM;
  const unsigned short* w2e = w2t + (size_t)e * DIM * IDIM;
  const unsigned short* gA0 = He + (size_t)(m0 + sr0) * IDIM + sk;
  const unsigned short* gA1 = He + (size_t)(m0 + sr1) * IDIM + sk;
  const unsigned short* gB0 = w2e + (size_t)(n0 + sr0) * IDIM + sk;
  const unsigned short* gB1 = w2e + (size_t)(n0 + sr1) * IDIM + sk;

  int lane16 = lane & 15;
  int quad   = lane >> 4;
  int wm = (wave & 1) * 64;
  int wn = (wave >> 1) * 64;

  floatx4 acc[4][4];
#pragma unroll
  for (int i = 0; i < 4; i++)
#pragma unroll
    for (int j = 0; j < 4; j++) acc[i][j] = (floatx4){0.f, 0.f, 0.f, 0.f};

  for (int k0 = 0; k0 < IDIM; k0 += 64) {
    __syncthreads();
#pragma unroll
    for (int b = 0; b < 2; b++) {
      int kk = k0 + b * 32;
      async16(gA0 + kk, As[b] + (wave * 2 + 0) * 512);
      async16(gA1 + kk, As[b] + (wave * 2 + 1) * 512);
      async16(gB0 + kk, Bs[b] + (wave * 2 + 0) * 512);
      async16(gB1 + kk, Bs[b] + (wave * 2 + 1) * 512);
    }
    __syncthreads();

#pragma unroll
    for (int b = 0; b < 2; b++) {
      short8 a[4];
#pragma unroll
      for (int i = 0; i < 4; i++)
        a[i] = *(const short8*)&As[b][(wm + i * 16 + lane16) * 32 + quad * 8];
#pragma unroll
      for (int j = 0; j < 4; j++) {
        short8 bb = *(const short8*)&Bs[b][(wn + j * 16 + lane16) * 32 + quad * 8];
#pragma unroll
        for (int i = 0; i < 4; i++)
          acc[i][j] = __builtin_amdgcn_mfma_f32_16x16x32_bf16(a[i], bb, acc[i][j], 0, 0, 0);
      }
    }
  }

#pragma unroll
  for (int i = 0; i < 4; i++) {
#pragma unroll
    for (int r = 0; r < 4; r++) {
      int m = m0 + wm + i * 16 + quad * 4 + r;
      if (m < cnte) {
        int tok = rowtok[e * CAP + m];
        float g = rowgate[e * CAP + m];
        float* orow = out + (size_t)tok * DIM;
#pragma unroll
        for (int j = 0; j < 4; j++) {
          int n = n0 + wn + j * 16 + lane16;
          atomicAdd(&orow[n], g * acc[i][j][r]);
        }
      }
    }
  }
}

// ---------------- launch ----------------
extern "C" void kernel_launch(void* const* d_in, const int* in_sizes, int n_in,
                              void* d_out, int out_size, void* d_ws, size_t ws_size,
                              hipStream_t stream) {
  const float* x  = (const float*)d_in[0];
  const float* Wg = (const float*)d_in[1];
  const float* W1 = (const float*)d_in[2];
  const float* W2 = (const float*)d_in[3];
  float* out = (float*)d_out;

  char* ws = (char*)d_ws;
  size_t off = 0;
  auto alloc = [&](size_t bytes) -> void* {
    void* p = ws + off;
    off = (off + bytes + 255) & ~(size_t)255;
    return p;
  };
  int*   top_i   = (int*)alloc((size_t)N_TOK * 2 * sizeof(int));
  float* gates   = (float*)alloc((size_t)N_TOK * 2 * sizeof(float));
  int*   rowtok  = (int*)alloc((size_t)NEXP * CAP * sizeof(int));
  float* rowgate = (float*)alloc((size_t)NEXP * CAP * sizeof(float));
  int*   cnt     = (int*)alloc((size_t)NEXP * sizeof(int));
  unsigned short* xb  = (unsigned short*)alloc((size_t)N_TOK * DIM * 2);
  unsigned short* w1t = (unsigned short*)alloc((size_t)NEXP * TWOI * DIM * 2);
  unsigned short* w2t = (unsigned short*)alloc((size_t)NEXP * DIM * IDIM * 2);
  unsigned short* Hb  = (unsigned short*)alloc((size_t)NEXP * CAP * IDIM * 2);
  if (off > ws_size) return;

  hipLaunchKernelGGL(prologue_kernel, dim3(W1_BLOCKS + ROUTER_BLOCKS), dim3(256), 0, stream,
                     W1, w1t, x, Wg, xb, top_i, gates, out);
  hipLaunchKernelGGL(scan_kernel, dim3(1), dim3(1024), 0, stream,
                     top_i, gates, rowtok, rowgate, cnt);
  hipLaunchKernelGGL(gemm1_kernel, dim3(G1X, G1Y, NEXP + G1_TRANS_Z), dim3(256), 0, stream,
                     xb, w1t, rowtok, cnt, Hb, W2, w2t);
  hipLaunchKernelGGL(gemm2_kernel, dim3(DIM / 128, CAP / 128, NEXP), dim3(256), 0, stream,
                     Hb, w2t, cnt, rowtok, rowgate, out);
}